// Round 6
// baseline (311.473 us; speedup 1.0000x reference)
//
#include <hip/hip_runtime.h>

#define NCLASS 100
#define TROWS 64       // rows per tile == threads per block (1 wave)
#define CHUNKS 25      // float4 chunks per row

typedef float fx4 __attribute__((ext_vector_type(4)));

// Register-reduce-then-LDS-transpose, sized for FULL residency:
// LDS 8.4 KB -> 16 single-wave blocks/CU; grid 4096 = 16 x 256 CUs all
// resident from t=0 -> no retirement tail. launch_bounds(64,4) caps VGPR<=128.
__global__ __launch_bounds__(64, 4) void argmax_hist_kernel(
    const fx4* __restrict__ g4,
    unsigned int* __restrict__ counts,
    int nrows)
{
    __shared__ float         part_m[TROWS * CHUNKS];   // 6400 B
    __shared__ unsigned char part_c[TROWS * CHUNKS];   // 1600 B
    __shared__ unsigned int  lhist[NCLASS];            //  400 B

    const int tid = threadIdx.x;
    #pragma unroll
    for (int i = tid; i < NCLASS; i += TROWS) lhist[i] = 0u;
    __syncthreads();

    const int ntiles = nrows / TROWS;         // 65536 exactly
    fx4 stg[CHUNKS];

    int tile = blockIdx.x;
    if (tile < ntiles) {                      // prologue: stage tile 0
        const size_t b4 = (size_t)tile * (TROWS * CHUNKS);
        #pragma unroll
        for (int i = 0; i < CHUNKS; ++i)
            stg[i] = __builtin_nontemporal_load(&g4[b4 + i * TROWS + tid]);
    }

    while (tile < ntiles) {
        // ---- per-chunk argmax in regs; linear (max, col) writes to LDS ----
        #pragma unroll
        for (int i = 0; i < CHUNKS; ++i) {
            const fx4 v = stg[i];
            float m = v.x; int ci = 0;
            if (v.y > m) { m = v.y; ci = 1; }     // element order => first max in chunk
            if (v.z > m) { m = v.z; ci = 2; }
            if (v.w > m) { m = v.w; ci = 3; }
            const int f = i * TROWS + tid;        // == row*25 + chunk  (linear)
            const int c = f % CHUNKS;             // chunk index within row
            part_m[f] = m;
            part_c[f] = (unsigned char)(4 * c + ci);
        }

        // ---- issue NEXT tile's loads; they fly during the row-reduce ----
        const int ntile = tile + gridDim.x;
        if (ntile < ntiles) {
            const size_t b4 = (size_t)ntile * (TROWS * CHUNKS);
            #pragma unroll
            for (int i = 0; i < CHUNKS; ++i)
                stg[i] = __builtin_nontemporal_load(&g4[b4 + i * TROWS + tid]);
        }

        __syncthreads();   // order partial writes before row reads (1 wave: cheap)

        // ---- row-reduce: thread t scans row t's 25 (max,col) in chunk order ----
        const int rb = tid * CHUNKS;
        float best = -__builtin_huge_valf();
        int bcol = 0;
        #pragma unroll
        for (int j = 0; j < CHUNKS; ++j) {
            const float m = part_m[rb + j];
            if (m > best) { best = m; bcol = part_c[rb + j]; }  // strict > => first occurrence
        }
        atomicAdd(&lhist[bcol], 1u);

        __syncthreads();   // reads done before next iteration's writes
        tile = ntile;
    }

    // ---- flush histogram once per block ----
    #pragma unroll
    for (int i = tid; i < NCLASS; i += TROWS) {
        unsigned int c = lhist[i];
        if (c) atomicAdd(&counts[i], c);
    }
}

// Entropy from counts. Single block of 128 threads.
__global__ __launch_bounds__(128) void entropy_kernel(
    const unsigned int* __restrict__ counts,
    float* __restrict__ out,
    float invB)
{
    __shared__ float partial[128];
    const int t = threadIdx.x;
    float term = 0.0f;
    if (t < NCLASS) {
        float c = (float)counts[t];
        if (c > 0.0f) {
            float p = c * invB;
            term = p * (logf(p) * 1.4426950408889634f);  // p * log2(p)
        }
    }
    partial[t] = term;
    __syncthreads();
    #pragma unroll
    for (int s = 64; s > 0; s >>= 1) {
        if (t < s) partial[t] += partial[t + s];
        __syncthreads();
    }
    if (t == 0) out[0] = -partial[0];
}

extern "C" void kernel_launch(void* const* d_in, const int* in_sizes, int n_in,
                              void* d_out, int out_size, void* d_ws, size_t ws_size,
                              hipStream_t stream)
{
    const float* logits = (const float*)d_in[0];
    const int nrows = in_sizes[0] / NCLASS;

    unsigned int* counts = (unsigned int*)d_ws;
    (void)hipMemsetAsync(counts, 0, NCLASS * sizeof(unsigned int), stream);

    const int grid = 4096;   // 16 blocks/CU, all resident; 16 tiles per block
    argmax_hist_kernel<<<grid, TROWS, 0, stream>>>(
        (const fx4*)logits, counts, nrows);

    entropy_kernel<<<1, 128, 0, stream>>>(counts, (float*)d_out, 1.0f / (float)nrows);
}

// Round 7
// 286.338 us; speedup vs baseline: 1.0878x; 1.0878x over previous
//
#include <hip/hip_runtime.h>

#define NCLASS 100
#define TROWS 64       // rows per tile == threads per block (1 wave)
#define CHUNKS 25      // float4 chunks per row

typedef float fx4 __attribute__((ext_vector_type(4)));

// Double-buffered global_load_lds streaming (no VGPR staging, no barriers):
//   issue 25 DMA loads -> buf[b^1] ; s_waitcnt vmcnt(25) (older 25 done) ;
//   row-scan buf[b] from LDS ; flip.
// In-flight bytes/wave = 25.6 KB (vs 400 B with VGPR staging) -> Little's-law
// saturation of the HBM read path with only 3 single-wave blocks/CU.
__global__ __launch_bounds__(64) void argmax_hist_kernel(
    const fx4* __restrict__ g4,
    unsigned int* __restrict__ counts,
    int nrows)
{
    __shared__ fx4 buf[2][CHUNKS * TROWS];   // 2 x 25600 B
    __shared__ unsigned int lhist[NCLASS];   // 400 B  -> 51.6 KB total, 3 blocks/CU

    const int tid = threadIdx.x;
    #pragma unroll
    for (int i = tid; i < NCLASS; i += TROWS) lhist[i] = 0u;
    __syncthreads();

    const int ntiles = nrows / TROWS;        // 65536 exactly
    const int stride = gridDim.x;

    // DMA one 64x100 tile into buf[b]: instruction i writes LDS chunks
    // [i*64, i*64+64) from global chunks [tile*1600 + i*64 + lane].
    // LDS dest is wave-uniform base + lane*16 (HW rule); global src is per-lane.
    #define ISSUE_TILE(b_, tile_)                                               \
        {                                                                       \
            const fx4* src = g4 + (size_t)(tile_) * (CHUNKS * TROWS) + tid;     \
            _Pragma("unroll")                                                   \
            for (int i = 0; i < CHUNKS; ++i) {                                  \
                __builtin_amdgcn_global_load_lds(                               \
                    (const __attribute__((address_space(1))) void*)(src + i * TROWS), \
                    (__attribute__((address_space(3))) void*)(&buf[(b_)][i * TROWS]), \
                    16, 0, 0);                                                  \
            }                                                                   \
        }

    int tile = blockIdx.x;
    int b = 0;
    if (tile < ntiles) ISSUE_TILE(0, tile);

    while (tile < ntiles) {
        const int nxt = tile + stride;
        const bool has_next = (nxt < ntiles);
        if (has_next) {
            ISSUE_TILE(b ^ 1, nxt);
            // 50 outstanding; wait until <=25 -> the 25 for buf[b] have landed.
            asm volatile("s_waitcnt vmcnt(25)" ::: "memory");
        } else {
            asm volatile("s_waitcnt vmcnt(0)" ::: "memory");
        }
        __builtin_amdgcn_sched_barrier(0);   // keep reads below the wait

        // ---- row-scan: thread t reads row t (25 fx4) in column order ----
        const fx4* rp = &buf[b][tid * CHUNKS];   // row-major [64][100] floats
        float best = -__builtin_huge_valf();
        int bcol = 0;
        #pragma unroll
        for (int j = 0; j < CHUNKS; ++j) {
            const fx4 v = rp[j];
            if (v.x > best) { best = v.x; bcol = 4 * j + 0; }  // strict > => first max
            if (v.y > best) { best = v.y; bcol = 4 * j + 1; }
            if (v.z > best) { best = v.z; bcol = 4 * j + 2; }
            if (v.w > best) { best = v.w; bcol = 4 * j + 3; }
        }
        atomicAdd(&lhist[bcol], 1u);

        b ^= 1;
        tile = nxt;
    }

    // ---- flush histogram once per block ----
    #pragma unroll
    for (int i = tid; i < NCLASS; i += TROWS) {
        unsigned int c = lhist[i];
        if (c) atomicAdd(&counts[i], c);
    }
    #undef ISSUE_TILE
}

// Entropy from counts. Single block of 128 threads.
__global__ __launch_bounds__(128) void entropy_kernel(
    const unsigned int* __restrict__ counts,
    float* __restrict__ out,
    float invB)
{
    __shared__ float partial[128];
    const int t = threadIdx.x;
    float term = 0.0f;
    if (t < NCLASS) {
        float c = (float)counts[t];
        if (c > 0.0f) {
            float p = c * invB;
            term = p * (logf(p) * 1.4426950408889634f);  // p * log2(p)
        }
    }
    partial[t] = term;
    __syncthreads();
    #pragma unroll
    for (int s = 64; s > 0; s >>= 1) {
        if (t < s) partial[t] += partial[t + s];
        __syncthreads();
    }
    if (t == 0) out[0] = -partial[0];
}

extern "C" void kernel_launch(void* const* d_in, const int* in_sizes, int n_in,
                              void* d_out, int out_size, void* d_ws, size_t ws_size,
                              hipStream_t stream)
{
    const float* logits = (const float*)d_in[0];
    const int nrows = in_sizes[0] / NCLASS;

    unsigned int* counts = (unsigned int*)d_ws;
    (void)hipMemsetAsync(counts, 0, NCLASS * sizeof(unsigned int), stream);

    const int grid = 768;   // 3 blocks/CU (LDS-capped), ~85 tiles per block
    argmax_hist_kernel<<<grid, TROWS, 0, stream>>>(
        (const fx4*)logits, counts, nrows);

    entropy_kernel<<<1, 128, 0, stream>>>(counts, (float*)d_out, 1.0f / (float)nrows);
}